// Round 1
// 231.762 us; speedup vs baseline: 1.0111x; 1.0111x over previous
//
#include <hip/hip_runtime.h>
#include <math.h>

// HR_HLIFLayer2D: leaky integrate-and-fire over T=32 timesteps.
// x: (B=16, T=32, C=64, H=32, W=32) f32; vth_raw/decay_raw: (C,H,W) f32.
// out: spikes (B,T,C,H,W) f32 in {0.0, 1.0}.
//
// R3: (a) float4 (16 B/lane — vmem sweet spot; halves vmem instruction count
// vs R2's float2; 1024 blocks = 16 waves/CU which still covers the ~10 KB/CU
// in-flight-bytes requirement at 6.3 TB/s), (b) per-neuron params (softplus/
// sigmoid in f64) precomputed once into d_ws by a tiny kernel instead of
// redundantly B=16x per neuron in the hot kernel, (c) nontemporal loads on x
// (stream-once data; keep it out of L2/L3 alongside the nt spike stream).
//
// Numerics: recurrence uses explicit __fmul_rn/__fadd_rn/__fsub_rn to match
// the fp32 reference op order exactly (no FMA contraction). Params computed
// with double transcendentals, rounded once to fp32 per reference op sequence
// (verified absmax == 0.0 in R2 with identical math).

#define LIF_B    16
#define LIF_T    32
#define LIF_CHW  65536   // 64*32*32
#define LIF_CHW4 16384   // CHW / 4

typedef float vf4 __attribute__((ext_vector_type(4)));

__device__ __forceinline__ float lif_vth_f(float raw) {
    // vth = softplus(raw*0.1 + 0.5) + 0.01, fp32 rounding sequence
    float a  = __fmul_rn(raw, 0.1f);
    float bb = __fadd_rn(a, 0.5f);
    double sp = log1p(exp((double)bb));          // correctly-rounded softplus
    return __fadd_rn((float)sp, 0.01f);
}

__device__ __forceinline__ float lif_dec_f(float raw) {
    // decay = clip(sigmoid(raw*0.1 + 2.0), 0, 0.99)
    float z = __fmul_rn(raw, 0.1f);
    float w = __fadd_rn(z, 2.0f);
    double sg = 1.0 / (1.0 + exp(-(double)w));
    float sgf = (float)sg;
    return fminf(fmaxf(sgf, 0.0f), 0.99f);       // clip never binds in practice
}

// Tiny precompute kernel: wp[0:CHW) = vth, wp[CHW:2*CHW) = decay.
__global__ __launch_bounds__(256) void lif_params_kernel(
    const float* __restrict__ vth_raw,
    const float* __restrict__ decay_raw,
    float* __restrict__ wp)
{
    const int i = blockIdx.x * 256 + threadIdx.x;   // [0, CHW)
    wp[i]           = lif_vth_f(vth_raw[i]);
    wp[i + LIF_CHW] = lif_dec_f(decay_raw[i]);
}

// Main kernel. PRE=true: p_vth/p_dec are precomputed tables (workspace).
// PRE=false: p_vth/p_dec are the raw params, computed inline (ws fallback).
template<bool PRE>
__global__ __launch_bounds__(256) void HR_HLIFLayer2D_kernel(
    const float* __restrict__ x,
    const float* __restrict__ p_vth,
    const float* __restrict__ p_dec,
    float* __restrict__ out)
{
    const int g = blockIdx.x * 256 + threadIdx.x;   // [0, B*CHW4)
    const int b = g >> 14;                          // g / CHW4
    const int j = g & (LIF_CHW4 - 1);               // float4 index within CHW

    const vf4 rv = reinterpret_cast<const vf4*>(p_vth)[j];
    const vf4 rd = reinterpret_cast<const vf4*>(p_dec)[j];

    float vth[4], dec[4];
    {
        const float rva[4] = {rv.x, rv.y, rv.z, rv.w};
        const float rda[4] = {rd.x, rd.y, rd.z, rd.w};
#pragma unroll
        for (int i = 0; i < 4; ++i) {
            vth[i] = PRE ? rva[i] : lif_vth_f(rva[i]);
            dec[i] = PRE ? rda[i] : lif_dec_f(rda[i]);
        }
    }

    float v[4] = {0.f, 0.f, 0.f, 0.f};
    const size_t base4 = (size_t)b * (LIF_T * LIF_CHW4) + (size_t)j;
    const vf4* __restrict__ x4 = reinterpret_cast<const vf4*>(x);
    vf4* __restrict__ o4 = reinterpret_cast<vf4*>(out);

    // depth-2 software pipeline: xt holds x_t, prefetch x_{t+1} before compute.
    // Full unroll lets the compiler cluster loads further ahead on top of this.
    vf4 xt = __builtin_nontemporal_load(&x4[base4]);
#pragma unroll
    for (int t = 0; t < LIF_T; ++t) {
        const size_t idx = base4 + (size_t)t * LIF_CHW4;
        vf4 xn;
        if (t + 1 < LIF_T)                           // compile-time branch (full unroll)
            xn = __builtin_nontemporal_load(&x4[idx + LIF_CHW4]);

        const float xi[4] = {xt.x, xt.y, xt.z, xt.w};
        float so[4];
#pragma unroll
        for (int i = 0; i < 4; ++i) {
            // v = v*decay + x_t   (separate mul, add — match ref rounding)
            float vv = __fadd_rn(__fmul_rn(v[i], dec[i]), xi[i]);
            // s = (v - vth > 0) ? 1 : 0
            float d = __fsub_rn(vv, vth[i]);
            const bool fire = (d > 0.0f);
            so[i] = fire ? 1.0f : 0.0f;
            // v = v - s*vth: s=1 -> exactly d (fl(v - vth)); s=0 -> exactly vv
            v[i] = fire ? d : vv;
        }
        vf4 s; s.x = so[0]; s.y = so[1]; s.z = so[2]; s.w = so[3];
        __builtin_nontemporal_store(s, &o4[idx]);    // spikes never re-read
        xt = xn;
    }
}

extern "C" void kernel_launch(void* const* d_in, const int* in_sizes, int n_in,
                              void* d_out, int out_size, void* d_ws, size_t ws_size,
                              hipStream_t stream) {
    const float* x         = (const float*)d_in[0];
    const float* vth_raw   = (const float*)d_in[1];
    const float* decay_raw = (const float*)d_in[2];
    float* out             = (float*)d_out;

    const int grid = (LIF_B * LIF_CHW4) / 256;       // 1024 blocks

    if (ws_size >= (size_t)(2 * LIF_CHW * sizeof(float))) {
        float* wp = (float*)d_ws;
        lif_params_kernel<<<LIF_CHW / 256, 256, 0, stream>>>(vth_raw, decay_raw, wp);
        HR_HLIFLayer2D_kernel<true><<<grid, 256, 0, stream>>>(x, wp, wp + LIF_CHW, out);
    } else {
        // Workspace too small: compute params inline (R2 behavior, float4).
        HR_HLIFLayer2D_kernel<false><<<grid, 256, 0, stream>>>(x, vth_raw, decay_raw, out);
    }
}